// Round 2
// baseline (116.668 us; speedup 1.0000x reference)
//
#include <hip/hip_runtime.h>
#include <math.h>

#define NN   65536
#define DEGC 16
#define DD   64
#define DD2  128
#define BB   1024
#define NEGC 10
#define NROWS (2 * BB + NEGC)      // 2058
#define NEDGE (NROWS * DEGC)       // 32928

__device__ __forceinline__ float rl(float v, int i) {
    return __uint_as_float(__builtin_amdgcn_readlane(__float_as_uint(v), i));
}

// ---------------------------------------------------------------------------
// Mark + compact: unique hop-1 node list via bitmap CAS + wave-aggregated append.
// ---------------------------------------------------------------------------
__global__ __launch_bounds__(256) void mark_compact_kernel(
    const int* __restrict__ adj,
    const int* __restrict__ in1, const int* __restrict__ in2,
    const int* __restrict__ neg,
    int* __restrict__ flags, int* __restrict__ list, int* __restrict__ count) {

    int e = blockIdx.x * 256 + threadIdx.x;
    int nbr = 0;
    bool isnew = false;
    if (e < NEDGE) {
        int r = e >> 4, k = e & 15;
        int node = (r < BB) ? in1[r] : (r < 2 * BB ? in2[r - BB] : neg[r - 2 * BB]);
        nbr = adj[node * DEGC + k];
        int old = atomicCAS(&flags[nbr], 0, 1);
        isnew = (old == 0);
    }
    unsigned long long mask = __ballot(isnew);
    if (mask) {
        int lane = threadIdx.x & 63;
        int cnt = __popcll(mask);
        int leader = __ffsll((long long)mask) - 1;
        int base = 0;
        if (lane == leader) base = atomicAdd(count, cnt);
        base = __shfl(base, leader, 64);
        if (isnew) {
            int pos = __popcll(mask & ((1ull << lane) - 1));
            list[base + pos] = nbr;
        }
    }
}

// ---------------------------------------------------------------------------
// Hop-1 over compacted list. 4 nodes per wave per chunk.
// W1 in LDS padded [128][65] (conflict-free read & staging write).
// Concat vector stays in registers; broadcast via v_readlane -> SGPR FMA.
// ---------------------------------------------------------------------------
__global__ __launch_bounds__(256) void hop1_kernel(
    const float* __restrict__ feat, const int* __restrict__ adj,
    const float* __restrict__ W1, const float* __restrict__ b1,
    const int* __restrict__ list, const int* __restrict__ count_p,
    float* __restrict__ h1) {

    __shared__ float wt[DD2 * 65];        // wt[i*65+j] = W1[j][i], 33.3 KB

    int tid = threadIdx.x;
    #pragma unroll
    for (int t = 0; t < (DD2 * DD) / 256; ++t) {
        int lin = t * 256 + tid;
        int i = lin & 127, j = lin >> 7;   // consecutive lanes: i consecutive
        wt[i * 65 + j] = W1[j * DD2 + i];  // global read coalesced; LDS bank (i+j)%32
    }
    __syncthreads();

    int lane = tid & 63;
    int wid = blockIdx.x * 4 + (tid >> 6);
    int nwaves = gridDim.x * 4;
    int count = *count_p;
    float bias = b1[lane];

    for (int base = wid * 4; base < count; base += nwaves * 4) {
        int nb = min(4, count - base);
        int ns[4];
        float cself[4], csum[4];
        #pragma unroll
        for (int m = 0; m < 4; ++m) {
            cself[m] = 0.f; csum[m] = 0.f; ns[m] = 0;
            if (m < nb) {
                int n = __builtin_amdgcn_readfirstlane(list[base + m]);
                ns[m] = n;
                const int* arow = adj + n * DEGC;
                float s = 0.f;
                #pragma unroll
                for (int k = 0; k < DEGC; ++k)
                    s += feat[arow[k] * DD + lane];
                cself[m] = feat[n * DD + lane];
                csum[m] = s;
            }
        }
        float acc[4] = {bias, bias, bias, bias};
        #pragma unroll
        for (int i = 0; i < DD; ++i) {
            float w = wt[i * 65 + lane];
            #pragma unroll
            for (int m = 0; m < 4; ++m)
                acc[m] += rl(cself[m], i) * w;
        }
        #pragma unroll
        for (int i = 0; i < DD; ++i) {
            float w = wt[(DD + i) * 65 + lane];
            #pragma unroll
            for (int m = 0; m < 4; ++m)
                acc[m] += rl(csum[m], i) * w;
        }
        #pragma unroll
        for (int m = 0; m < 4; ++m)
            if (m < nb)
                h1[ns[m] * DD + lane] = tanhf(acc[m]);
    }
}

// ---------------------------------------------------------------------------
// Hop-2: 2 rows per wave. W2 in LDS with XOR swizzle (64 KB exactly).
// wt2[i*128 + (j ^ (i&31))] = W2[j][i]; lane owns outputs j=lane and j=lane+64.
// ---------------------------------------------------------------------------
__global__ __launch_bounds__(256) void hop2_kernel(
    const float* __restrict__ feat, const int* __restrict__ adj,
    const float* __restrict__ h1,
    const int* __restrict__ in1, const int* __restrict__ in2,
    const int* __restrict__ neg,
    const float* __restrict__ W2, const float* __restrict__ b2,
    float* __restrict__ out) {

    __shared__ float wt2[DD2 * DD2];      // 64 KB

    int tid = threadIdx.x;
    #pragma unroll
    for (int t = 0; t < (DD2 * DD2) / 256; ++t) {
        int lin = t * 256 + tid;
        int i = lin & 127, j = lin >> 7;   // lanes: i consecutive -> coalesced read
        wt2[i * DD2 + (j ^ (i & 31))] = W2[j * DD2 + i];  // bank varies with i
    }
    __syncthreads();

    int lane = tid & 63;
    int wid = blockIdx.x * 4 + (tid >> 6);

    float cself[2], csum[2];
    int rr[2];
    #pragma unroll
    for (int m = 0; m < 2; ++m) {
        int r = wid * 2 + m;
        rr[m] = r;
        cself[m] = 0.f; csum[m] = 0.f;
        if (r < NROWS) {
            int node = (r < BB) ? in1[r] : (r < 2 * BB ? in2[r - BB] : neg[r - 2 * BB]);
            node = __builtin_amdgcn_readfirstlane(node);
            const int* arow = adj + node * DEGC;
            float s = 0.f;
            #pragma unroll
            for (int k = 0; k < DEGC; ++k)
                s += h1[arow[k] * DD + lane];
            cself[m] = feat[node * DD + lane];
            csum[m] = s;
        }
    }

    float accA[2] = {b2[lane], b2[lane]};
    float accB[2] = {b2[DD + lane], b2[DD + lane]};
    #pragma unroll
    for (int i = 0; i < DD; ++i) {
        int sw = lane ^ (i & 31);
        float wa = wt2[i * DD2 + sw];
        float wb = wt2[i * DD2 + 64 + sw];
        #pragma unroll
        for (int m = 0; m < 2; ++m) {
            float ci = rl(cself[m], i);
            accA[m] += ci * wa;
            accB[m] += ci * wb;
        }
    }
    #pragma unroll
    for (int i = 0; i < DD; ++i) {
        int sw = lane ^ (i & 31);
        float wa = wt2[(DD + i) * DD2 + sw];
        float wb = wt2[(DD + i) * DD2 + 64 + sw];
        #pragma unroll
        for (int m = 0; m < 2; ++m) {
            float ci = rl(csum[m], i);
            accA[m] += ci * wa;
            accB[m] += ci * wb;
        }
    }

    #pragma unroll
    for (int m = 0; m < 2; ++m) {
        if (rr[m] < NROWS) {
            float ss = accA[m] * accA[m] + accB[m] * accB[m];
            #pragma unroll
            for (int off = 32; off > 0; off >>= 1) ss += __shfl_xor(ss, off, 64);
            float inv = 1.0f / fmaxf(sqrtf(ss), 1e-12f);
            out[rr[m] * DD2 + lane]      = accA[m] * inv;
            out[rr[m] * DD2 + DD + lane] = accB[m] * inv;
        }
    }
}

// ---------------------------------------------------------------------------
extern "C" void kernel_launch(void* const* d_in, const int* in_sizes, int n_in,
                              void* d_out, int out_size, void* d_ws, size_t ws_size,
                              hipStream_t stream) {
    const float* feat = (const float*)d_in[0];
    const int*   adj  = (const int*)d_in[1];
    const int*   in1  = (const int*)d_in[2];
    const int*   in2  = (const int*)d_in[3];
    const int*   neg  = (const int*)d_in[4];
    const float* W1   = (const float*)d_in[5];
    const float* b1   = (const float*)d_in[6];
    const float* W2   = (const float*)d_in[7];
    const float* b2   = (const float*)d_in[8];
    float* out = (float*)d_out;

    // ws layout
    float* h1   = (float*)d_ws;                                       // 16 MB
    char*  p    = (char*)d_ws + (size_t)NN * DD * sizeof(float);
    int*   flags = (int*)p;                                           // 256 KB
    int*   list  = (int*)(p + (size_t)NN * sizeof(int));              // 128 KB
    int*   count = (int*)(p + (size_t)NN * sizeof(int) + NEDGE * sizeof(int));

    hipMemsetAsync(flags, 0, (size_t)NN * sizeof(int) + NEDGE * sizeof(int) + 4, stream);
    mark_compact_kernel<<<(NEDGE + 255) / 256, 256, 0, stream>>>(
        adj, in1, in2, neg, flags, list, count);
    hop1_kernel<<<1024, 256, 0, stream>>>(feat, adj, W1, b1, list, count, h1);
    hop2_kernel<<<(NROWS + 7) / 8, 256, 0, stream>>>(
        feat, adj, h1, in1, in2, neg, W2, b2, out);
}